// Round 1
// baseline (1257.317 us; speedup 1.0000x reference)
//
#include <hip/hip_runtime.h>

// Detection post-process: softmax -> decode -> per-class sequential NMS (100 steps) -> top-100.
// N=8 images, A=16384 anchors, C=21 classes (class 0 = background).

#define N_IMG 8
#define A     16384
#define NCLS  21
#define NC    (NCLS - 1)   // 20 foreground classes
#define TOPK  100
#define PROB_THR 0.05f
#define NMS_THR  0.45f

// Block-wide argmax with lowest-index tie-break (matches jnp.argmax / lax.top_k).
// rv/ri must have >= blockDim.x/64 slots. Safe for repeated calls (entry barrier
// protects scratch reuse).
__device__ __forceinline__ void block_argmax(float& v, int& i, float* rv, int* ri) {
    __syncthreads();
#pragma unroll
    for (int off = 32; off > 0; off >>= 1) {
        float ov = __shfl_down(v, off, 64);
        int   oi = __shfl_down(i, off, 64);
        if (ov > v || (ov == v && oi < i)) { v = ov; i = oi; }
    }
    const int w = threadIdx.x >> 6;
    if ((threadIdx.x & 63) == 0) { rv[w] = v; ri[w] = i; }
    __syncthreads();
    const int nw = blockDim.x >> 6;
    v = rv[0]; i = ri[0];
    for (int k = 1; k < nw; ++k) {
        float ov = rv[k]; int oi = ri[k];
        if (ov > v || (ov == v && oi < i)) { v = ov; i = oi; }
    }
}

// Kernel 1: softmax + threshold -> scores[N][NC][A]; SSD decode -> clamped corner boxes[N*A] (float4).
__global__ __launch_bounds__(256) void preprocess_kernel(
    const float* __restrict__ cls, const float* __restrict__ reg,
    const float* __restrict__ anc, float4* __restrict__ boxes,
    float* __restrict__ scores) {
    const int t = blockIdx.x * blockDim.x + threadIdx.x;
    if (t >= N_IMG * A) return;
    const int n = t >> 14;          // A = 2^14
    const int a = t & (A - 1);

    const float* c = cls + (size_t)t * NCLS;
    float z[NCLS];
    float m = -1e30f;
#pragma unroll
    for (int k = 0; k < NCLS; ++k) { z[k] = c[k]; m = fmaxf(m, z[k]); }
    float s = 0.f;
#pragma unroll
    for (int k = 0; k < NCLS; ++k) { z[k] = expf(z[k] - m); s += z[k]; }
    const float inv = 1.f / s;
#pragma unroll
    for (int k = 0; k < NC; ++k) {
        float p = z[k + 1] * inv;
        scores[(((size_t)n * NC + k) << 14) + a] = (p > PROB_THR) ? p : -1.f;
    }

    const float4 l4 = ((const float4*)reg)[t];
    const float4 an = ((const float4*)anc)[a];
    const float cx = an.x + l4.x * 0.1f * an.z;
    const float cy = an.y + l4.y * 0.1f * an.w;
    const float w  = an.z * expf(l4.z * 0.2f);
    const float h  = an.w * expf(l4.w * 0.2f);
    float x0 = fminf(fmaxf(cx - 0.5f * w, 0.f), 1.f);
    float y0 = fminf(fmaxf(cy - 0.5f * h, 0.f), 1.f);
    float x1 = fminf(fmaxf(cx + 0.5f * w, 0.f), 1.f);
    float y1 = fminf(fmaxf(cy + 0.5f * h, 0.f), 1.f);
    boxes[t] = make_float4(x0, y0, x1, y1);
}

// Kernel 2: one workgroup per (n, ci). Scores slice in LDS; fused kill+next-argmax sweep.
// Thread-ownership of LDS float4 entries (j mod 512) -> no barriers needed on sc4 itself.
__global__ __launch_bounds__(512) void nms_kernel(
    const float4* __restrict__ boxes, const float* __restrict__ scores,
    float* __restrict__ rows) {
    __shared__ float4 sc4[A / 4];   // 64 KB (gfx950: 160 KB/WG available)
    __shared__ float rv[8];
    __shared__ int   ri[8];
    float* scf = (float*)sc4;

    const int blk = blockIdx.x;            // n * NC + ci
    const int n   = blk / NC;
    const int ci  = blk % NC;
    const int tid = threadIdx.x;
    const float4* gs4 = (const float4*)(scores + ((size_t)blk << 14));
    const float4* gb  = boxes + ((size_t)n << 14);
    float* grows = rows + (size_t)blk * (TOPK * 6);

    // Load scores into LDS + initial argmax (ascending-i visit order keeps first max).
    float bv = -1e30f; int bi = A;
    for (int j = tid; j < A / 4; j += 512) {
        float4 v = gs4[j];
        sc4[j] = v;
        const int i0 = j << 2;
        if (v.x > bv) { bv = v.x; bi = i0; }
        if (v.y > bv) { bv = v.y; bi = i0 + 1; }
        if (v.z > bv) { bv = v.z; bi = i0 + 2; }
        if (v.w > bv) { bv = v.w; bi = i0 + 3; }
    }
    block_argmax(bv, bi, rv, ri);

    for (int step = 0; step < TOPK; ++step) {
        if (bv <= 0.f) {            // uniform: all remaining rows are zeros
            for (int j = step * 6 + tid; j < TOPK * 6; j += 512) grows[j] = 0.f;
            return;
        }
        const float4 sel = gb[bi];  // broadcast load
        if (tid == 0) {
            grows[step * 6 + 0] = sel.x;
            grows[step * 6 + 1] = sel.y;
            grows[step * 6 + 2] = sel.z;
            grows[step * 6 + 3] = sel.w;
            grows[step * 6 + 4] = bv;
            grows[step * 6 + 5] = (float)(ci + 1);
        }
        const float asel = (sel.z - sel.x) * (sel.w - sel.y);
        const int kbi = bi;
        float nv = -1e30f; int ni = A;
        for (int j = tid; j < A / 4; j += 512) {
            float4 v = sc4[j];
            const int i0 = j << 2;
#pragma unroll
            for (int c = 0; c < 4; ++c) {
                float s = (c == 0) ? v.x : (c == 1) ? v.y : (c == 2) ? v.z : v.w;
                const int i = i0 + c;
                if (s > 0.f) {      // active anchors only touch boxes
                    const float4 b = gb[i];
                    float lx = fmaxf(sel.x, b.x), ly = fmaxf(sel.y, b.y);
                    float rx = fminf(sel.z, b.z), ry = fminf(sel.w, b.w);
                    float iw = fmaxf(rx - lx, 0.f), ih = fmaxf(ry - ly, 0.f);
                    float inter = iw * ih;
                    float ab = (b.z - b.x) * (b.w - b.y);
                    float un = asel + ab - inter;
                    float iou = (un > 0.f) ? (inter / un) : 0.f;
                    if (iou > NMS_THR || i == kbi) { scf[i] = -1.f; s = -1.f; }
                }
                if (s > nv) { nv = s; ni = i; }
            }
        }
        bv = nv; bi = ni;
        block_argmax(bv, bi, rv, ri);
    }
}

// Kernel 3: per image, iterative top-100 over the 2100 candidate scores
// (index j<100 = zero class-0 block; j>=100 -> rows[(j-100)]). Matches lax.top_k
// ordering: descending value, lowest index first on ties.
__global__ __launch_bounds__(256) void topk_kernel(
    const float* __restrict__ rows, float* __restrict__ out) {
    __shared__ float sc[NCLS * TOPK];   // 2100 floats
    __shared__ float rv[8];
    __shared__ int   ri[8];
    const int n = blockIdx.x;
    const int tid = threadIdx.x;
    const float* r = rows + (size_t)n * NC * TOPK * 6;

    for (int j = tid; j < NCLS * TOPK; j += 256)
        sc[j] = (j < TOPK) ? 0.f : r[(j - TOPK) * 6 + 4];

    for (int k = 0; k < TOPK; ++k) {
        __syncthreads();            // orders prior sc[idx] write vs. this scan
        float v = -1e30f; int idx = 1 << 30;
        for (int j = tid; j < NCLS * TOPK; j += 256) {
            float s = sc[j];
            if (s > v) { v = s; idx = j; }
        }
        block_argmax(v, idx, rv, ri);
        if (tid == 0) sc[idx] = -1e30f;
        if (tid < 6) {
            float o = 0.f;
            if (idx >= TOPK) o = r[(idx - TOPK) * 6 + tid];
            out[((size_t)n * TOPK + k) * 6 + tid] = o;
        }
    }
}

extern "C" void kernel_launch(void* const* d_in, const int* in_sizes, int n_in,
                              void* d_out, int out_size, void* d_ws, size_t ws_size,
                              hipStream_t stream) {
    const float* cls = (const float*)d_in[0];   // [8,16384,21]
    const float* reg = (const float*)d_in[1];   // [8,16384,4]
    const float* anc = (const float*)d_in[2];   // [16384,4]
    float* out = (float*)d_out;                 // [8,100,6]

    // ws layout (floats): boxes 524288 | scores 2621440 | rows 96000  (~12.4 MB)
    float* boxes  = (float*)d_ws;
    float* scores = boxes + (size_t)N_IMG * A * 4;
    float* rows   = scores + (size_t)N_IMG * NC * A;

    preprocess_kernel<<<(N_IMG * A) / 256, 256, 0, stream>>>(cls, reg, anc, (float4*)boxes, scores);
    nms_kernel<<<N_IMG * NC, 512, 0, stream>>>((const float4*)boxes, scores, rows);
    topk_kernel<<<N_IMG, 256, 0, stream>>>(rows, out);
}

// Round 2
// 560.209 us; speedup vs baseline: 2.2444x; 2.2444x over previous
//
#include <hip/hip_runtime.h>

// Detection post-process: softmax -> decode -> per-class sequential NMS (100 steps) -> top-100.
// N=8 images, A=16384 anchors, C=21 classes (class 0 = background).
//
// NMS strategy (R1): active set is fixed at start (scores only die), so compact
// (score, box) for active anchors into LDS once; each of the 100 sequential steps
// is then a pure LDS sweep (fused kill + next-argmax). Stable compaction keeps
// ascending anchor order -> compacted-index tie-breaks == anchor-index tie-breaks.

#define N_IMG 8
#define A     16384
#define NCLS  21
#define NC    (NCLS - 1)   // 20 foreground classes
#define TOPK  100
#define PROB_THR 0.05f
#define NMS_THR  0.45f

#define TNMS   1024        // threads in nms block (16 waves)
#define CHUNK  (A / TNMS)  // 16 anchors per thread (contiguous -> stable compaction)
#define CAP    8160        // fast-path capacity: 8160 * 20 B = 163200 B LDS
#define SMEMF  40800       // CAP * 5 floats

// Block-wide argmax, lowest-index tie-break (matches jnp.argmax / lax.top_k).
__device__ __forceinline__ void block_argmax(float& v, int& i, float* rv, int* ri, int nthreads) {
    __syncthreads();
#pragma unroll
    for (int off = 32; off > 0; off >>= 1) {
        float ov = __shfl_down(v, off, 64);
        int   oi = __shfl_down(i, off, 64);
        if (ov > v || (ov == v && oi < i)) { v = ov; i = oi; }
    }
    const int w = threadIdx.x >> 6;
    if ((threadIdx.x & 63) == 0) { rv[w] = v; ri[w] = i; }
    __syncthreads();
    const int nw = nthreads >> 6;
    v = rv[0]; i = ri[0];
    for (int k = 1; k < nw; ++k) {
        float ov = rv[k]; int oi = ri[k];
        if (ov > v || (ov == v && oi < i)) { v = ov; i = oi; }
    }
}

// Kernel 1: softmax + threshold -> scores[N][NC][A]; SSD decode -> clamped corner boxes (float4).
__global__ __launch_bounds__(256) void preprocess_kernel(
    const float* __restrict__ cls, const float* __restrict__ reg,
    const float* __restrict__ anc, float4* __restrict__ boxes,
    float* __restrict__ scores) {
    const int t = blockIdx.x * blockDim.x + threadIdx.x;
    if (t >= N_IMG * A) return;
    const int n = t >> 14;          // A = 2^14
    const int a = t & (A - 1);

    const float* c = cls + (size_t)t * NCLS;
    float z[NCLS];
    float m = -1e30f;
#pragma unroll
    for (int k = 0; k < NCLS; ++k) { z[k] = c[k]; m = fmaxf(m, z[k]); }
    float s = 0.f;
#pragma unroll
    for (int k = 0; k < NCLS; ++k) { z[k] = expf(z[k] - m); s += z[k]; }
    const float inv = 1.f / s;
#pragma unroll
    for (int k = 0; k < NC; ++k) {
        float p = z[k + 1] * inv;
        scores[(((size_t)n * NC + k) << 14) + a] = (p > PROB_THR) ? p : -1.f;
    }

    const float4 l4 = ((const float4*)reg)[t];
    const float4 an = ((const float4*)anc)[a];
    const float cx = an.x + l4.x * 0.1f * an.z;
    const float cy = an.y + l4.y * 0.1f * an.w;
    const float w  = an.z * expf(l4.z * 0.2f);
    const float h  = an.w * expf(l4.w * 0.2f);
    float x0 = fminf(fmaxf(cx - 0.5f * w, 0.f), 1.f);
    float y0 = fminf(fmaxf(cy - 0.5f * h, 0.f), 1.f);
    float x1 = fminf(fmaxf(cx + 0.5f * w, 0.f), 1.f);
    float y1 = fminf(fmaxf(cy + 0.5f * h, 0.f), 1.f);
    boxes[t] = make_float4(x0, y0, x1, y1);
}

// Kernel 2: one workgroup per (n, ci). Compact active (score, box) into LDS, then
// 100 steps of fused kill+argmax LDS sweeps.
__global__ __launch_bounds__(TNMS) void nms_kernel(
    const float4* __restrict__ boxes, const float* __restrict__ scores,
    float* __restrict__ rows) {
    __shared__ float smem[SMEMF];        // fast: score[CAP] | float4 box[CAP]; slow: score[A] | int idx[A]
    __shared__ float rv[TNMS / 64];
    __shared__ int   ri[TNMS / 64];
    __shared__ int   wsum[TNMS / 64 + 1];

    const int blk = blockIdx.x;          // n * NC + ci
    const int n   = blk / NC;
    const int ci  = blk % NC;
    const int tid = threadIdx.x;
    const int lane = tid & 63;
    const int w    = tid >> 6;
    const float* gs  = scores + ((size_t)blk << 14);
    const float4* gb = boxes + ((size_t)n << 14);
    float* grows = rows + (size_t)blk * (TOPK * 6);

    // --- Stable compaction: thread t owns anchors [t*CHUNK, (t+1)*CHUNK) ---
    float ls[CHUNK];
    int cnt = 0;
#pragma unroll
    for (int k = 0; k < CHUNK; ++k) {
        ls[k] = gs[tid * CHUNK + k];
        if (ls[k] > 0.f) ++cnt;
    }
    // exclusive scan of cnt across the block
    int inc = cnt;
#pragma unroll
    for (int off = 1; off < 64; off <<= 1) {
        int o = __shfl_up(inc, off, 64);
        if (lane >= off) inc += o;
    }
    if (lane == 63) wsum[w] = inc;
    __syncthreads();
    if (tid == 0) {
        int acc = 0;
#pragma unroll
        for (int k = 0; k < TNMS / 64; ++k) { int t2 = wsum[k]; wsum[k] = acc; acc += t2; }
        wsum[TNMS / 64] = acc;
    }
    __syncthreads();
    int base = wsum[w] + inc - cnt;
    const int M = wsum[TNMS / 64];
    const bool fast = (M <= CAP);

    float*  sscore = smem;
    float4* sbox   = (float4*)(smem + CAP);   // fast path only
    int*    sidx   = (int*)(smem + A);        // slow path only

    float bv = -1e30f; int bi = 1 << 30;
    if (fast) {
#pragma unroll
        for (int k = 0; k < CHUNK; ++k) {
            if (ls[k] > 0.f) {
                sscore[base] = ls[k];
                sbox[base]   = gb[tid * CHUNK + k];
                if (ls[k] > bv) { bv = ls[k]; bi = base; }
                ++base;
            }
        }
    } else {
#pragma unroll
        for (int k = 0; k < CHUNK; ++k) {
            if (ls[k] > 0.f) {
                sscore[base] = ls[k];
                sidx[base]   = tid * CHUNK + k;
                if (ls[k] > bv) { bv = ls[k]; bi = base; }
                ++base;
            }
        }
    }
    block_argmax(bv, bi, rv, ri, TNMS);       // entry barrier also fences the compaction writes

    // --- 100 sequential NMS steps, all LDS-resident in the fast path ---
    for (int step = 0; step < TOPK; ++step) {
        if (bv <= 0.f) {                      // uniform: remaining rows are zeros
            for (int j = step * 6 + tid; j < TOPK * 6; j += TNMS) grows[j] = 0.f;
            return;
        }
        const float4 sel = fast ? sbox[bi] : gb[sidx[bi]];   // LDS/L2 broadcast
        if (tid == 0) {
            grows[step * 6 + 0] = sel.x;
            grows[step * 6 + 1] = sel.y;
            grows[step * 6 + 2] = sel.z;
            grows[step * 6 + 3] = sel.w;
            grows[step * 6 + 4] = bv;
            grows[step * 6 + 5] = (float)(ci + 1);
        }
        const float asel = (sel.z - sel.x) * (sel.w - sel.y);
        const int kbi = bi;
        float nv = -1e30f; int ni = 1 << 30;
        if (fast) {
            for (int j = tid; j < M; j += TNMS) {
                float s = sscore[j];
                if (s > 0.f) {
                    const float4 b = sbox[j];
                    float lx = fmaxf(sel.x, b.x), ly = fmaxf(sel.y, b.y);
                    float rx = fminf(sel.z, b.z), ry = fminf(sel.w, b.w);
                    float iw = fmaxf(rx - lx, 0.f), ih = fmaxf(ry - ly, 0.f);
                    float inter = iw * ih;
                    float ab = (b.z - b.x) * (b.w - b.y);
                    float un = asel + ab - inter;
                    float iou = (un > 0.f) ? (inter / un) : 0.f;   // keep exact ref math (div)
                    if (iou > NMS_THR || j == kbi) { sscore[j] = -1.f; s = -1.f; }
                }
                if (s > nv) { nv = s; ni = j; }
            }
        } else {
            for (int j = tid; j < M; j += TNMS) {
                float s = sscore[j];
                if (s > 0.f) {
                    const float4 b = gb[sidx[j]];
                    float lx = fmaxf(sel.x, b.x), ly = fmaxf(sel.y, b.y);
                    float rx = fminf(sel.z, b.z), ry = fminf(sel.w, b.w);
                    float iw = fmaxf(rx - lx, 0.f), ih = fmaxf(ry - ly, 0.f);
                    float inter = iw * ih;
                    float ab = (b.z - b.x) * (b.w - b.y);
                    float un = asel + ab - inter;
                    float iou = (un > 0.f) ? (inter / un) : 0.f;
                    if (iou > NMS_THR || j == kbi) { sscore[j] = -1.f; s = -1.f; }
                }
                if (s > nv) { nv = s; ni = j; }
            }
        }
        bv = nv; bi = ni;
        block_argmax(bv, bi, rv, ri, TNMS);
    }
}

// Kernel 3: per image, iterative top-100 over the 2100 candidate scores
// (j<100 = zero class-0 block; j>=100 -> rows[j-100]). Matches lax.top_k ordering.
__global__ __launch_bounds__(256) void topk_kernel(
    const float* __restrict__ rows, float* __restrict__ out) {
    __shared__ float sc[NCLS * TOPK];
    __shared__ float rv[4];
    __shared__ int   ri[4];
    const int n = blockIdx.x;
    const int tid = threadIdx.x;
    const float* r = rows + (size_t)n * NC * TOPK * 6;

    for (int j = tid; j < NCLS * TOPK; j += 256)
        sc[j] = (j < TOPK) ? 0.f : r[(j - TOPK) * 6 + 4];

    for (int k = 0; k < TOPK; ++k) {
        __syncthreads();            // orders prior sc[idx] write vs. this scan
        float v = -1e30f; int idx = 1 << 30;
        for (int j = tid; j < NCLS * TOPK; j += 256) {
            float s = sc[j];
            if (s > v) { v = s; idx = j; }
        }
        block_argmax(v, idx, rv, ri, 256);
        if (tid == 0) sc[idx] = -1e30f;
        if (tid < 6) {
            float o = 0.f;
            if (idx >= TOPK) o = r[(idx - TOPK) * 6 + tid];
            out[((size_t)n * TOPK + k) * 6 + tid] = o;
        }
    }
}

extern "C" void kernel_launch(void* const* d_in, const int* in_sizes, int n_in,
                              void* d_out, int out_size, void* d_ws, size_t ws_size,
                              hipStream_t stream) {
    const float* cls = (const float*)d_in[0];   // [8,16384,21]
    const float* reg = (const float*)d_in[1];   // [8,16384,4]
    const float* anc = (const float*)d_in[2];   // [16384,4]
    float* out = (float*)d_out;                 // [8,100,6]

    // ws layout (floats): boxes 524288 | scores 2621440 | rows 96000  (~12.9 MB)
    float* boxes  = (float*)d_ws;
    float* scores = boxes + (size_t)N_IMG * A * 4;
    float* rows   = scores + (size_t)N_IMG * NC * A;

    preprocess_kernel<<<(N_IMG * A) / 256, 256, 0, stream>>>(cls, reg, anc, (float4*)boxes, scores);
    nms_kernel<<<N_IMG * NC, TNMS, 0, stream>>>((const float4*)boxes, scores, rows);
    topk_kernel<<<N_IMG, 256, 0, stream>>>(rows, out);
}

// Round 3
// 395.765 us; speedup vs baseline: 3.1769x; 1.4155x over previous
//
#include <hip/hip_runtime.h>

// Detection post-process: softmax -> decode -> per-class batched sequential NMS -> top-100.
// N=8 images, A=16384 anchors, C=21 classes (class 0 = background).
//
// R2 lesson: cost ∝ number of sweeps (per-sweep serial scaffolding ~9k cyc), not bytes.
// R3: batch top-4 extraction per sweep (exact: sorted top-4 of survivors contains the
// next argmax chain; validate candidates pairwise), boxes register-resident, u64-packed
// keys for exact (score desc, index asc) ordering, division-free EXACT IoU predicate:
//   RN_f32(inter/un) > 0.45f  <=>  (double)inter > ((double)0.45f + 2^-26) * (double)un
// (26-bit x 24-bit product exact in f64; midpoint tie rounds to even = 0.45f -> false.)

typedef unsigned long long u64;

#define N_IMG 8
#define A     16384
#define NCLS  21
#define NC    20
#define TOPK  100
#define PROB_THR 0.05f

#define TNMS  1024
#define CHUNK 16          // A / TNMS
#define CAP   8160        // fast-path capacity (M ~ 4800 expected)
#define RSLOT 8           // ceil(CAP / TNMS)

#define MIDTHR ((double)0.45f + 0x1p-26)

__device__ __forceinline__ u64 pk(float v, int i) {
    return (v > 0.f) ? (((u64)__float_as_uint(v) << 32) | (u64)(unsigned)(~(unsigned)i)) : 0ull;
}
__device__ __forceinline__ float upv(u64 k) { return __uint_as_float((unsigned)(k >> 32)); }
__device__ __forceinline__ int   upi(u64 k) { return (int)(~(unsigned)k); }

// insert key into sorted-desc 4-list (keys unique; dead = 0)
__device__ __forceinline__ void ins4(u64 t[4], u64 key) {
    if (key > t[3]) {
        t[3] = key;
        if (t[3] > t[2]) { u64 x = t[2]; t[2] = t[3]; t[3] = x; }
        if (t[2] > t[1]) { u64 x = t[1]; t[1] = t[2]; t[2] = x; }
        if (t[1] > t[0]) { u64 x = t[0]; t[0] = t[1]; t[1] = x; }
    }
}

__device__ __forceinline__ u64 umx(u64 a, u64 b) { return a > b ? a : b; }
__device__ __forceinline__ u64 umn(u64 a, u64 b) { return a < b ? a : b; }

// butterfly merge level: my sorted-4 + partner's sorted-4 -> sorted top-4 of union
__device__ __forceinline__ void mrg(u64 t[4], int mask) {
    u64 o0 = __shfl_xor(t[0], mask, 64);
    u64 o1 = __shfl_xor(t[1], mask, 64);
    u64 o2 = __shfl_xor(t[2], mask, 64);
    u64 o3 = __shfl_xor(t[3], mask, 64);
    u64 a0 = umx(t[0], o3), a1 = umx(t[1], o2), a2 = umx(t[2], o1), a3 = umx(t[3], o0);
    u64 b0 = umx(a0, a2), b2 = umn(a0, a2), b1 = umx(a1, a3), b3 = umn(a1, a3);
    t[0] = umx(b0, b1); t[1] = umn(b0, b1); t[2] = umx(b2, b3); t[3] = umn(b2, b3);
}

// exact ref predicate: RN(inter/union) > 0.45f   (entry box b/area ab vs selected s/area as_)
__device__ __forceinline__ bool killp(float4 b, float ab, float4 s, float as_) {
    float lx = fmaxf(s.x, b.x), ly = fmaxf(s.y, b.y);
    float rx = fminf(s.z, b.z), ry = fminf(s.w, b.w);
    float iw = fmaxf(rx - lx, 0.f), ih = fmaxf(ry - ly, 0.f);
    float inter = iw * ih;
    float un = as_ + ab - inter;       // matches ref (area_sel + area_all) - inter
    return (double)inter > MIDTHR * (double)un;
}

// block-wide exact top-4 (sorted desc). red: u64[64] LDS, cres: u64[4] LDS.
template <int NWAVES>
__device__ __forceinline__ void block_top4(u64 t[4], u64* red, u64* cres, int tid) {
    mrg(t, 1); mrg(t, 2); mrg(t, 4); mrg(t, 8); mrg(t, 16); mrg(t, 32);
    const int lane = tid & 63, w = tid >> 6;
    if (lane < 4) {
        u64 x = lane == 0 ? t[0] : lane == 1 ? t[1] : lane == 2 ? t[2] : t[3];
        red[(w << 2) + lane] = x;
    }
    __syncthreads();
    if (tid < 64) {
        u64 s[4] = { (tid < NWAVES * 4) ? red[tid] : 0ull, 0ull, 0ull, 0ull };
        mrg(s, 1); mrg(s, 2); mrg(s, 4); mrg(s, 8); mrg(s, 16); mrg(s, 32);
        if (tid < 4) {
            u64 x = tid == 0 ? s[0] : tid == 1 ? s[1] : tid == 2 ? s[2] : s[3];
            cres[tid] = x;
        }
    }
    __syncthreads();
}

// Kernel 1: softmax + threshold -> scores[N][NC][A]; SSD decode -> clamped corner boxes.
// UNCHANGED from R1/R2 (bit-exact vs np reference, absmax 0.0).
__global__ __launch_bounds__(256) void preprocess_kernel(
    const float* __restrict__ cls, const float* __restrict__ reg,
    const float* __restrict__ anc, float4* __restrict__ boxes,
    float* __restrict__ scores) {
    const int t = blockIdx.x * blockDim.x + threadIdx.x;
    if (t >= N_IMG * A) return;
    const int n = t >> 14;
    const int a = t & (A - 1);

    const float* c = cls + (size_t)t * NCLS;
    float z[NCLS];
    float m = -1e30f;
#pragma unroll
    for (int k = 0; k < NCLS; ++k) { z[k] = c[k]; m = fmaxf(m, z[k]); }
    float s = 0.f;
#pragma unroll
    for (int k = 0; k < NCLS; ++k) { z[k] = expf(z[k] - m); s += z[k]; }
    const float inv = 1.f / s;
#pragma unroll
    for (int k = 0; k < NC; ++k) {
        float p = z[k + 1] * inv;
        scores[(((size_t)n * NC + k) << 14) + a] = (p > PROB_THR) ? p : -1.f;
    }

    const float4 l4 = ((const float4*)reg)[t];
    const float4 an = ((const float4*)anc)[a];
    const float cx = an.x + l4.x * 0.1f * an.z;
    const float cy = an.y + l4.y * 0.1f * an.w;
    const float w  = an.z * expf(l4.z * 0.2f);
    const float h  = an.w * expf(l4.w * 0.2f);
    float x0 = fminf(fmaxf(cx - 0.5f * w, 0.f), 1.f);
    float y0 = fminf(fmaxf(cy - 0.5f * h, 0.f), 1.f);
    float x1 = fminf(fmaxf(cx + 0.5f * w, 0.f), 1.f);
    float y1 = fminf(fmaxf(cy + 0.5f * h, 0.f), 1.f);
    boxes[t] = make_float4(x0, y0, x1, y1);
}

// Kernel 2: one workgroup per (n, ci). Compact -> registers -> batched top-4 NMS sweeps.
__global__ __launch_bounds__(TNMS) void nms_kernel(
    const float4* __restrict__ boxes, float* __restrict__ scores,
    float* __restrict__ rows) {
    // sscore[8192] | sbox[CAP] (float4; reused as red/cres/cbx after register load)
    __shared__ __align__(16) float smem[8192 + CAP * 4];
    __shared__ int wsum[17];

    float*  sscore = smem;
    float4* sbox   = (float4*)(smem + 8192);
    u64*    red    = (u64*)(smem + 8192);       // aliases sbox (after reg-load)
    u64*    cres   = red + 64;
    float4* cbx    = (float4*)(cres + 4);

    const int blk = blockIdx.x, n = blk / NC, ci = blk % NC;
    const int tid = threadIdx.x;
    const int lane = tid & 63, w = tid >> 6;
    float* gs = scores + ((size_t)blk << 14);
    const float4* gb = boxes + ((size_t)n << 14);
    float* grows = rows + (size_t)blk * 600;

    // --- stable compaction (ascending anchor order -> exact tie-break preservation) ---
    float ls[CHUNK];
    int cnt = 0;
#pragma unroll
    for (int k = 0; k < CHUNK; ++k) {
        ls[k] = gs[tid * CHUNK + k];
        if (ls[k] > 0.f) ++cnt;
    }
    int inc = cnt;
#pragma unroll
    for (int off = 1; off < 64; off <<= 1) {
        int o = __shfl_up(inc, off, 64);
        if (lane >= off) inc += o;
    }
    if (lane == 63) wsum[w] = inc;
    __syncthreads();
    if (tid == 0) {
        int acc = 0;
#pragma unroll
        for (int k2 = 0; k2 < 16; ++k2) { int tmp = wsum[k2]; wsum[k2] = acc; acc += tmp; }
        wsum[16] = acc;
    }
    __syncthreads();
    int base = wsum[w] + inc - cnt;
    const int M = wsum[16];

    if (M <= CAP) {
        // ---------------- fast path ----------------
#pragma unroll
        for (int k = 0; k < CHUNK; ++k)
            if (ls[k] > 0.f) { sscore[base] = ls[k]; sbox[base] = gb[tid * CHUNK + k]; ++base; }
        for (int j = M + tid; j < 8192; j += TNMS) sscore[j] = -1.f;   // pad dead
        __syncthreads();

        // boxes to registers: entry e owned by thread e&1023, slot e>>10
        float4 rb[RSLOT];
#pragma unroll
        for (int k = 0; k < RSLOT; ++k) {
            int e = (k << 10) + tid;
            if (e < M) rb[k] = sbox[e];
        }
        __syncthreads();            // sbox region free -> red/cres/cbx

        const int KU = (M + TNMS - 1) >> 10;   // uniform slot count

        // initial scan (no kills)
        u64 t4[4] = {0ull, 0ull, 0ull, 0ull};
#pragma unroll
        for (int k = 0; k < RSLOT; ++k) {
            if (k < KU) {
                int e = (k << 10) + tid;
                ins4(t4, pk(sscore[e], e));
            }
        }
        block_top4<16>(t4, red, cres, tid);

        int emitted = 0;
        while (true) {
            float cv[4]; int cidx[4];
#pragma unroll
            for (int c = 0; c < 4; ++c) { u64 kk = cres[c]; cv[c] = upv(kk); cidx[c] = upi(kk); }
            // owners publish candidate boxes
#pragma unroll
            for (int c = 0; c < 4; ++c) {
                if (cv[c] > 0.f && (cidx[c] & (TNMS - 1)) == tid) {
                    int slot = cidx[c] >> 10;
                    float4 b = rb[0];
#pragma unroll
                    for (int k = 1; k < RSLOT; ++k) if (slot == k) b = rb[k];
                    cbx[c] = b;
                }
            }
            __syncthreads();
            float4 cb[4]; float abc[4];
#pragma unroll
            for (int c = 0; c < 4; ++c) {
                cb[c] = cbx[c];
                abc[c] = (cb[c].z - cb[c].x) * (cb[c].w - cb[c].y);
            }
            // validate batch (uniform scalar walk: candidate accepted iff it survives
            // all previously-accepted candidates in this batch)
            bool acc[4];
            int na = 0;
            const int room = TOPK - emitted;
#pragma unroll
            for (int c = 0; c < 4; ++c) {
                bool ok = (cv[c] > 0.f) && (na < room);
                if (ok) {
#pragma unroll
                    for (int a2 = 0; a2 < c; ++a2)
                        if (acc[a2] && killp(cb[c], abc[c], cb[a2], abc[a2])) ok = false;
                }
                acc[c] = ok;
                na += ok ? 1 : 0;
            }
            if (na == 0) {          // best <= 0: remaining rows are zeros (matches ref)
                for (int j = emitted * 6 + tid; j < 600; j += TNMS) grows[j] = 0.f;
                return;
            }
            if (tid == 0) {
                int pos = emitted;
#pragma unroll
                for (int c = 0; c < 4; ++c) {
                    if (acc[c]) {
                        float* o = grows + pos * 6;
                        o[0] = cb[c].x; o[1] = cb[c].y; o[2] = cb[c].z; o[3] = cb[c].w;
                        o[4] = cv[c];   o[5] = (float)(ci + 1);
                        ++pos;
                    }
                }
            }
            emitted += na;
            if (emitted >= TOPK) return;

            // kill sweep (register boxes, owner-only LDS score updates) + next top-4
            u64 s4[4] = {0ull, 0ull, 0ull, 0ull};
#pragma unroll
            for (int k = 0; k < RSLOT; ++k) {
                if (k < KU) {
                    int e = (k << 10) + tid;
                    float s = sscore[e];
                    if (s > 0.f) {
                        float4 b = rb[k];
                        float ab = (b.z - b.x) * (b.w - b.y);
                        bool dead = false;
#pragma unroll
                        for (int c = 0; c < 4; ++c)
                            if (acc[c] && ((e == cidx[c]) || killp(b, ab, cb[c], abc[c]))) dead = true;
                        if (dead) { sscore[e] = -1.f; s = -1.f; }
                    }
                    ins4(s4, pk(s, e));
                }
            }
            block_top4<16>(s4, red, cres, tid);
        }
    } else {
        // ---------------- slow fallback (M > CAP; ~never) ----------------
        // global-memory sweeps, one selection per sweep, exact semantics.
        u64 t4[4] = {0ull, 0ull, 0ull, 0ull};
        for (int j = tid; j < A; j += TNMS) ins4(t4, pk(gs[j], j));
        block_top4<16>(t4, red, cres, tid);
        int emitted = 0;
        while (true) {
            u64 kk = cres[0];
            float cv = upv(kk); int cj = upi(kk);
            if (cv <= 0.f) {
                for (int j = emitted * 6 + tid; j < 600; j += TNMS) grows[j] = 0.f;
                return;
            }
            if (tid == 0) cbx[0] = gb[cj];
            __syncthreads();
            float4 sb = cbx[0];
            float sa = (sb.z - sb.x) * (sb.w - sb.y);
            if (tid == 0) {
                float* o = grows + emitted * 6;
                o[0] = sb.x; o[1] = sb.y; o[2] = sb.z; o[3] = sb.w;
                o[4] = cv;   o[5] = (float)(ci + 1);
            }
            ++emitted;
            if (emitted >= TOPK) return;
            u64 s4[4] = {0ull, 0ull, 0ull, 0ull};
            for (int j = tid; j < A; j += TNMS) {
                float s = gs[j];
                if (s > 0.f) {
                    float4 b = gb[j];
                    float ab = (b.z - b.x) * (b.w - b.y);
                    if (j == cj || killp(b, ab, sb, sa)) { gs[j] = -1.f; s = -1.f; }
                }
                ins4(s4, pk(s, j));
            }
            block_top4<16>(s4, red, cres, tid);
        }
    }
}

// Kernel 3: per image, batched top-4 x 25 rounds over 2100 candidates (exact lax.top_k
// order). Zero-score selections emit all-zero rows (identical to ref output values).
__global__ __launch_bounds__(256) void topk_kernel(
    const float* __restrict__ rows, float* __restrict__ out) {
    __shared__ __align__(16) u64 red[64];
    __shared__ u64 cres[4];
    const int n = blockIdx.x, tid = threadIdx.x;
    const float* r = rows + (size_t)n * (NC * TOPK * 6);

    float rs[9];
#pragma unroll
    for (int k = 0; k < 9; ++k) {
        int e = (k << 8) + tid;
        float s = -1.f;
        if (e < NCLS * TOPK) s = (e < TOPK) ? 0.f : r[(e - TOPK) * 6 + 4];
        rs[k] = s;
    }
    for (int round = 0; round < 25; ++round) {
        u64 t4[4] = {0ull, 0ull, 0ull, 0ull};
#pragma unroll
        for (int k = 0; k < 9; ++k) ins4(t4, pk(rs[k], (k << 8) + tid));
        block_top4<4>(t4, red, cres, tid);
        float cv[4]; int cidx[4];
#pragma unroll
        for (int c = 0; c < 4; ++c) { u64 kk = cres[c]; cv[c] = upv(kk); cidx[c] = upi(kk); }
        // remove extracted entries (owner-local, registers)
#pragma unroll
        for (int c = 0; c < 4; ++c) {
            if (cv[c] > 0.f && (cidx[c] & 255) == tid) {
                int slot = cidx[c] >> 8;
#pragma unroll
                for (int k = 0; k < 9; ++k) if (k == slot) rs[k] = -1.f;
            }
        }
        if (tid < 24) {
            int c = tid / 6, f = tid - c * 6;
            float o = 0.f;
            if (cv[c] > 0.f && cidx[c] >= TOPK) o = r[(cidx[c] - TOPK) * 6 + f];
            out[((size_t)n * TOPK + round * 4 + c) * 6 + f] = o;
        }
    }
}

extern "C" void kernel_launch(void* const* d_in, const int* in_sizes, int n_in,
                              void* d_out, int out_size, void* d_ws, size_t ws_size,
                              hipStream_t stream) {
    const float* cls = (const float*)d_in[0];   // [8,16384,21]
    const float* reg = (const float*)d_in[1];   // [8,16384,4]
    const float* anc = (const float*)d_in[2];   // [16384,4]
    float* out = (float*)d_out;                 // [8,100,6]

    // ws layout (floats): boxes 524288 | scores 2621440 | rows 96000
    float* boxes  = (float*)d_ws;
    float* scores = boxes + (size_t)N_IMG * A * 4;
    float* rows   = scores + (size_t)N_IMG * NC * A;

    preprocess_kernel<<<(N_IMG * A) / 256, 256, 0, stream>>>(cls, reg, anc, (float4*)boxes, scores);
    nms_kernel<<<N_IMG * NC, TNMS, 0, stream>>>((const float4*)boxes, scores, rows);
    topk_kernel<<<N_IMG, 256, 0, stream>>>(rows, out);
}

// Round 4
// 356.596 us; speedup vs baseline: 3.5259x; 1.1098x over previous
//
#include <hip/hip_runtime.h>

// Detection post-process: softmax -> decode -> per-class batched sequential NMS -> top-100.
// N=8 images, A=16384 anchors, C=21 classes (class 0 = background).
//
// R3 lesson (counters): per-round cost = all-wave issue (sweep+merge+redundant validate)
// + lockstep stalls (3 barriers, wave0 phase2, owner-publish round trip).
// R4: wave0-only extract/validate/emit/plan; boxes resident in LDS (direct candidate
// fetch, no owner publish); 2 barriers/round; uniform-branch candidate skip.
// Top-k = 20-way merge of per-class sorted lists, one wave per image.
// Exact-semantics invariants kept from R3 (absmax 0.0):
//   - stable compaction => compact-index order == anchor-index order (tie-breaks)
//   - u64 key = (score_bits<<32)|~idx  => (score desc, idx asc) total order
//   - division-free EXACT IoU predicate:
//     RN_f32(inter/un) > 0.45f  <=>  (double)inter > ((double)0.45f + 2^-26)*(double)un

typedef unsigned long long u64;

#define N_IMG 8
#define A     16384
#define NCLS  21
#define NC    20
#define TOPK  100
#define PROB_THR 0.05f

#define TNMS  1024
#define CHUNK 16          // A / TNMS
#define CAP   8128        // LDS capacity: score[8192]*4 + box[8128]*16 = 162816 B (+scratch)
#define SPAD  8192
#define RSLOT 8           // ceil(CAP / TNMS)

#define MIDTHR ((double)0.45f + 0x1p-26)

__device__ __forceinline__ u64 pk(float v, int i) {
    return (v > 0.f) ? (((u64)__float_as_uint(v) << 32) | (u64)(unsigned)(~(unsigned)i)) : 0ull;
}
__device__ __forceinline__ float upv(u64 k) { return __uint_as_float((unsigned)(k >> 32)); }
__device__ __forceinline__ int   upi(u64 k) { return (int)(~(unsigned)k); }

// insert key into sorted-desc 4-list (dead = 0)
__device__ __forceinline__ void ins4(u64 t[4], u64 key) {
    if (key > t[3]) {
        t[3] = key;
        if (t[3] > t[2]) { u64 x = t[2]; t[2] = t[3]; t[3] = x; }
        if (t[2] > t[1]) { u64 x = t[1]; t[1] = t[2]; t[2] = x; }
        if (t[1] > t[0]) { u64 x = t[0]; t[0] = t[1]; t[1] = x; }
    }
}

__device__ __forceinline__ u64 umx(u64 a, u64 b) { return a > b ? a : b; }
__device__ __forceinline__ u64 umn(u64 a, u64 b) { return a < b ? a : b; }

// butterfly merge level: my sorted-4 + partner's sorted-4 -> sorted top-4 of union
__device__ __forceinline__ void mrg(u64 t[4], int mask) {
    u64 o0 = __shfl_xor(t[0], mask, 64);
    u64 o1 = __shfl_xor(t[1], mask, 64);
    u64 o2 = __shfl_xor(t[2], mask, 64);
    u64 o3 = __shfl_xor(t[3], mask, 64);
    u64 a0 = umx(t[0], o3), a1 = umx(t[1], o2), a2 = umx(t[2], o1), a3 = umx(t[3], o0);
    u64 b0 = umx(a0, a2), b2 = umn(a0, a2), b1 = umx(a1, a3), b3 = umn(a1, a3);
    t[0] = umx(b0, b1); t[1] = umn(b0, b1); t[2] = umx(b2, b3); t[3] = umn(b2, b3);
}
__device__ __forceinline__ void mrg6(u64 t[4]) {
    mrg(t, 1); mrg(t, 2); mrg(t, 4); mrg(t, 8); mrg(t, 16); mrg(t, 32);
}

// exact ref predicate: RN(inter/union) > 0.45f
__device__ __forceinline__ bool killp(float4 b, float ab, float4 s, float as_) {
    float lx = fmaxf(s.x, b.x), ly = fmaxf(s.y, b.y);
    float rx = fminf(s.z, b.z), ry = fminf(s.w, b.w);
    float iw = fmaxf(rx - lx, 0.f), ih = fmaxf(ry - ly, 0.f);
    float inter = iw * ih;
    float un = as_ + ab - inter;
    return (double)inter > MIDTHR * (double)un;
}

// block-wide exact top-4 (slow fallback path only)
__device__ __forceinline__ void block_top4(u64 t[4], u64* red, u64* cres, int tid) {
    mrg6(t);
    const int lane = tid & 63, w = tid >> 6;
    if (lane < 4) {
        u64 x = lane == 0 ? t[0] : lane == 1 ? t[1] : lane == 2 ? t[2] : t[3];
        red[(w << 2) + lane] = x;
    }
    __syncthreads();
    if (tid < 64) {
        u64 s[4] = { red[tid], 0ull, 0ull, 0ull };
        mrg6(s);
        if (tid < 4) {
            u64 x = tid == 0 ? s[0] : tid == 1 ? s[1] : tid == 2 ? s[2] : s[3];
            cres[tid] = x;
        }
    }
    __syncthreads();
}

// Kernel 1: softmax + threshold -> scores[N][NC][A]; SSD decode -> clamped corner boxes.
__global__ __launch_bounds__(256) void preprocess_kernel(
    const float* __restrict__ cls, const float* __restrict__ reg,
    const float* __restrict__ anc, float4* __restrict__ boxes,
    float* __restrict__ scores) {
    const int t = blockIdx.x * blockDim.x + threadIdx.x;
    if (t >= N_IMG * A) return;
    const int n = t >> 14;
    const int a = t & (A - 1);

    const float* c = cls + (size_t)t * NCLS;
    float z[NCLS];
    float m = -1e30f;
#pragma unroll
    for (int k = 0; k < NCLS; ++k) { z[k] = c[k]; m = fmaxf(m, z[k]); }
    float s = 0.f;
#pragma unroll
    for (int k = 0; k < NCLS; ++k) { z[k] = expf(z[k] - m); s += z[k]; }
    const float inv = 1.f / s;
#pragma unroll
    for (int k = 0; k < NC; ++k) {
        float p = z[k + 1] * inv;
        scores[(((size_t)n * NC + k) << 14) + a] = (p > PROB_THR) ? p : -1.f;
    }

    const float4 l4 = ((const float4*)reg)[t];
    const float4 an = ((const float4*)anc)[a];
    const float cx = an.x + l4.x * 0.1f * an.z;
    const float cy = an.y + l4.y * 0.1f * an.w;
    const float w  = an.z * expf(l4.z * 0.2f);
    const float h  = an.w * expf(l4.w * 0.2f);
    float x0 = fminf(fmaxf(cx - 0.5f * w, 0.f), 1.f);
    float y0 = fminf(fmaxf(cy - 0.5f * h, 0.f), 1.f);
    float x1 = fminf(fmaxf(cx + 0.5f * w, 0.f), 1.f);
    float y1 = fminf(fmaxf(cy + 0.5f * h, 0.f), 1.f);
    boxes[t] = make_float4(x0, y0, x1, y1);
}

// Kernel 2: one workgroup per (n, ci).
__global__ __launch_bounds__(TNMS) void nms_kernel(
    const float4* __restrict__ boxes, float* __restrict__ scores,
    float* __restrict__ rows) {
    __shared__ float sscore[SPAD];                    // 32768 B
    __shared__ __align__(16) float4 sbox[CAP];        // 130048 B
    __shared__ u64 red[64];
    __shared__ u64 plan_key[4];
    __shared__ __align__(16) float4 plan_box[4];
    __shared__ int plan_acc;
    __shared__ int wsum[17];

    const int blk = blockIdx.x, n = blk / NC, ci = blk % NC;
    const int tid = threadIdx.x;
    const int lane = tid & 63, w = tid >> 6;
    float* gs = scores + ((size_t)blk << 14);
    const float4* gb = boxes + ((size_t)n << 14);
    float* grows = rows + (size_t)blk * 600;

    // --- stable compaction (ascending anchor order) ---
    float ls[CHUNK];
    int cnt = 0;
#pragma unroll
    for (int k = 0; k < CHUNK; ++k) {
        ls[k] = gs[tid * CHUNK + k];
        if (ls[k] > 0.f) ++cnt;
    }
    int inc = cnt;
#pragma unroll
    for (int off = 1; off < 64; off <<= 1) {
        int o = __shfl_up(inc, off, 64);
        if (lane >= off) inc += o;
    }
    if (lane == 63) wsum[w] = inc;
    __syncthreads();
    if (tid == 0) {
        int acc = 0;
#pragma unroll
        for (int k2 = 0; k2 < 16; ++k2) { int tmp = wsum[k2]; wsum[k2] = acc; acc += tmp; }
        wsum[16] = acc;
    }
    __syncthreads();
    int base = wsum[w] + inc - cnt;
    const int M = wsum[16];

    if (M <= CAP) {
        // ---------------- fast path ----------------
#pragma unroll
        for (int k = 0; k < CHUNK; ++k)
            if (ls[k] > 0.f) { sscore[base] = ls[k]; sbox[base] = gb[tid * CHUNK + k]; ++base; }
        for (int j = M + tid; j < SPAD; j += TNMS) sscore[j] = -1.f;
        __syncthreads();

        // boxes also in registers for the sweep: entry e -> thread e&1023, slot e>>10
        float4 rb[RSLOT];
#pragma unroll
        for (int k = 0; k < RSLOT; ++k) {
            int e = (k << 10) + tid;
            if (e < M) rb[k] = sbox[e];
        }
        const int KU = (M + TNMS - 1) >> 10;

        // initial scan (no kills) -> per-wave top4 publish
        u64 t4[4] = {0ull, 0ull, 0ull, 0ull};
#pragma unroll
        for (int k = 0; k < RSLOT; ++k) {
            if (k < KU) {
                int e = (k << 10) + tid;
                ins4(t4, pk(sscore[e], e));
            }
        }
        mrg6(t4);
        if (lane < 4) {
            u64 x = lane == 0 ? t4[0] : lane == 1 ? t4[1] : lane == 2 ? t4[2] : t4[3];
            red[(w << 2) + lane] = x;
        }
        __syncthreads();

        int emitted = 0;
        while (true) {
            // ---- wave0: merge 64 keys, validate, emit, publish plan ----
            if (tid < 64) {
                u64 t[4] = { red[tid], 0ull, 0ull, 0ull };
                mrg6(t);                       // all 64 lanes hold sorted block-top4
                float cv[4]; int cidx[4];
#pragma unroll
                for (int c = 0; c < 4; ++c) { cv[c] = upv(t[c]); cidx[c] = upi(t[c]); }
                float4 bx = make_float4(0.f, 0.f, 0.f, 0.f);
                if (tid < 4 && cv[tid] > 0.f) bx = sbox[cidx[tid]];   // direct LDS fetch
                float4 cb[4]; float abc[4];
#pragma unroll
                for (int c = 0; c < 4; ++c) {
                    cb[c].x = __shfl(bx.x, c, 64);
                    cb[c].y = __shfl(bx.y, c, 64);
                    cb[c].z = __shfl(bx.z, c, 64);
                    cb[c].w = __shfl(bx.w, c, 64);
                    abc[c] = (cb[c].z - cb[c].x) * (cb[c].w - cb[c].y);
                }
                bool acc[4]; int na = 0, mask = 0;
                const int room = TOPK - emitted;
#pragma unroll
                for (int c = 0; c < 4; ++c) {
                    bool ok = (cv[c] > 0.f) && (na < room);
                    if (ok) {
#pragma unroll
                        for (int a2 = 0; a2 < c; ++a2)
                            if (acc[a2] && killp(cb[c], abc[c], cb[a2], abc[a2])) ok = false;
                    }
                    acc[c] = ok;
                    na += ok ? 1 : 0;
                    mask |= ok ? (1 << c) : 0;
                }
                if (tid < 4) {
                    plan_key[tid] = t[tid];
                    plan_box[tid] = bx;
                    if (acc[tid]) {
                        int rank = 0;
#pragma unroll
                        for (int a2 = 0; a2 < 4; ++a2) if (a2 < tid && acc[a2]) ++rank;
                        float* o = grows + (emitted + rank) * 6;
                        o[0] = bx.x; o[1] = bx.y; o[2] = bx.z; o[3] = bx.w;
                        o[4] = cv[tid]; o[5] = (float)(ci + 1);
                    }
                }
                if (tid == 0) plan_acc = mask;
            }
            __syncthreads();

            // ---- all threads: read plan, maybe exit, kill-sweep + next top4 ----
            const int mask = __builtin_amdgcn_readfirstlane(plan_acc);
            const int na = __popc(mask & 15);
            if (na == 0) {
                for (int j = emitted * 6 + tid; j < 600; j += TNMS) grows[j] = 0.f;
                return;
            }
            const u64 K0 = plan_key[0], K1 = plan_key[1], K2 = plan_key[2], K3 = plan_key[3];
            const float4 cb0 = plan_box[0], cb1 = plan_box[1], cb2 = plan_box[2], cb3 = plan_box[3];
            const int i0 = upi(K0), i1 = upi(K1), i2 = upi(K2), i3 = upi(K3);
            const float a0 = (cb0.z - cb0.x) * (cb0.w - cb0.y);
            const float a1 = (cb1.z - cb1.x) * (cb1.w - cb1.y);
            const float a2 = (cb2.z - cb2.x) * (cb2.w - cb2.y);
            const float a3 = (cb3.z - cb3.x) * (cb3.w - cb3.y);
            emitted += na;
            if (emitted >= TOPK) return;

            u64 s4[4] = {0ull, 0ull, 0ull, 0ull};
#pragma unroll
            for (int k = 0; k < RSLOT; ++k) {
                if (k < KU) {
                    int e = (k << 10) + tid;
                    float s = sscore[e];
                    if (s > 0.f) {
                        float4 b = rb[k];
                        float ab = (b.z - b.x) * (b.w - b.y);
                        bool dead = false;
                        if (mask & 1) dead = dead || (e == i0) || killp(b, ab, cb0, a0);
                        if (mask & 2) dead = dead || (e == i1) || killp(b, ab, cb1, a1);
                        if (mask & 4) dead = dead || (e == i2) || killp(b, ab, cb2, a2);
                        if (mask & 8) dead = dead || (e == i3) || killp(b, ab, cb3, a3);
                        if (dead) { sscore[e] = -1.f; s = -1.f; }
                    }
                    ins4(s4, pk(s, e));
                }
            }
            mrg6(s4);
            if (lane < 4) {
                u64 x = lane == 0 ? s4[0] : lane == 1 ? s4[1] : lane == 2 ? s4[2] : s4[3];
                red[(w << 2) + lane] = x;
            }
            __syncthreads();
        }
    } else {
        // ---------------- slow fallback (M > CAP; ~never) ----------------
        u64* cres = plan_key;
        u64 t4[4] = {0ull, 0ull, 0ull, 0ull};
        for (int j = tid; j < A; j += TNMS) ins4(t4, pk(gs[j], j));
        block_top4(t4, red, cres, tid);
        int emitted = 0;
        while (true) {
            u64 kk = cres[0];
            float cv = upv(kk); int cj = upi(kk);
            if (cv <= 0.f) {
                for (int j = emitted * 6 + tid; j < 600; j += TNMS) grows[j] = 0.f;
                return;
            }
            if (tid == 0) plan_box[0] = gb[cj];
            __syncthreads();
            float4 sb = plan_box[0];
            float sa = (sb.z - sb.x) * (sb.w - sb.y);
            if (tid == 0) {
                float* o = grows + emitted * 6;
                o[0] = sb.x; o[1] = sb.y; o[2] = sb.z; o[3] = sb.w;
                o[4] = cv;   o[5] = (float)(ci + 1);
            }
            ++emitted;
            if (emitted >= TOPK) return;
            u64 s4[4] = {0ull, 0ull, 0ull, 0ull};
            for (int j = tid; j < A; j += TNMS) {
                float s = gs[j];
                if (s > 0.f) {
                    float4 b = gb[j];
                    float ab = (b.z - b.x) * (b.w - b.y);
                    if (j == cj || killp(b, ab, sb, sa)) { gs[j] = -1.f; s = -1.f; }
                }
                ins4(s4, pk(s, j));
            }
            block_top4(s4, red, cres, tid);
        }
    }
}

// Kernel 3: per image, 20-way merge of per-class sorted row lists (1 wave / image).
// NMS rows are sorted desc by (score, index); reference flat tie-break is
// (score desc, ci*100+pos asc) -> one u64 key. Zero-score rows are all-zero, so
// once all heads are exhausted the remaining outputs are zero rows (== lax.top_k
// picking zero-score entries).
__global__ __launch_bounds__(64) void topk_kernel(
    const float* __restrict__ rows, float* __restrict__ out) {
    const int n = blockIdx.x, lane = threadIdx.x;
    const float* base = rows + (size_t)n * (NC * 600);
    float* o = out + (size_t)n * 600;

    float cur[6] = {0, 0, 0, 0, 0, 0}, nxt[6] = {0, 0, 0, 0, 0, 0};
    u64 ckey = 0, nkey = 0;
    int nextp = 2;
    if (lane < NC) {
        const float* r = base + lane * 600;
#pragma unroll
        for (int i = 0; i < 6; ++i) cur[i] = r[i];
        if (cur[4] > 0.f)
            ckey = ((u64)__float_as_uint(cur[4]) << 32) | (u64)(0xFFFFFFFFu - (unsigned)(lane * TOPK));
#pragma unroll
        for (int i = 0; i < 6; ++i) nxt[i] = r[6 + i];
        if (nxt[4] > 0.f)
            nkey = ((u64)__float_as_uint(nxt[4]) << 32) | (u64)(0xFFFFFFFFu - (unsigned)(lane * TOPK + 1));
    }
    for (int k = 0; k < TOPK; ++k) {
        u64 m = ckey;
#pragma unroll
        for (int off = 32; off > 0; off >>= 1) { u64 v = __shfl_xor(m, off, 64); m = m > v ? m : v; }
        if (m == 0ull) {
            for (int j = k * 6 + lane; j < 600; j += 64) o[j] = 0.f;
            return;
        }
        if (ckey == m) {                       // unique winner (codes distinct)
            float* d = o + k * 6;
#pragma unroll
            for (int i = 0; i < 6; ++i) d[i] = cur[i];
#pragma unroll
            for (int i = 0; i < 6; ++i) cur[i] = nxt[i];
            ckey = nkey;
            nkey = 0;
            if (nextp < TOPK) {                // prefetch next head
                const float* r = base + lane * 600 + nextp * 6;
#pragma unroll
                for (int i = 0; i < 6; ++i) nxt[i] = r[i];
                if (nxt[4] > 0.f)
                    nkey = ((u64)__float_as_uint(nxt[4]) << 32) |
                           (u64)(0xFFFFFFFFu - (unsigned)(lane * TOPK + nextp));
            }
            ++nextp;
        }
    }
}

extern "C" void kernel_launch(void* const* d_in, const int* in_sizes, int n_in,
                              void* d_out, int out_size, void* d_ws, size_t ws_size,
                              hipStream_t stream) {
    const float* cls = (const float*)d_in[0];   // [8,16384,21]
    const float* reg = (const float*)d_in[1];   // [8,16384,4]
    const float* anc = (const float*)d_in[2];   // [16384,4]
    float* out = (float*)d_out;                 // [8,100,6]

    // ws layout (floats): boxes 524288 | scores 2621440 | rows 96000
    float* boxes  = (float*)d_ws;
    float* scores = boxes + (size_t)N_IMG * A * 4;
    float* rows   = scores + (size_t)N_IMG * NC * A;

    preprocess_kernel<<<(N_IMG * A) / 256, 256, 0, stream>>>(cls, reg, anc, (float4*)boxes, scores);
    nms_kernel<<<N_IMG * NC, TNMS, 0, stream>>>((const float4*)boxes, scores, rows);
    topk_kernel<<<N_IMG, 64, 0, stream>>>(rows, out);
}

// Round 5
// 175.778 us; speedup vs baseline: 7.1529x; 2.0287x over previous
//
#include <hip/hip_runtime.h>

// Detection post-process: softmax -> decode -> per-class LAZY NMS -> top-100.
// N=8 images, A=16384 anchors, C=21 classes (class 0 = background).
//
// R4 lesson (counters): the 26-round loop's per-round u64 shuffle-merge tree
// (96 ds_permute/wave/round x 16 waves) serialized the LDS pipe -> 22.8k cyc/round.
// R5: kill the round loop. Lazy NMS: scores only die, and dead entries never kill
// (ref kills only from selected steps) => pop candidates in exact global
// (score desc, idx asc) order, test each against accepted boxes (<=100). One
// histogram-select + one bitonic sort + one serial walk. Exactness:
//   - u64 key = (score_bits<<32)|~idx  => exact total order, exact tie-breaks
//   - bin(float bits) monotone => bin-threshold selection is a key-order cut
//   - chunk refill via key<filter if chunk exhausts; degenerate single-extraction
//     path if one bin overflows the cap (never on real data, exact always)
//   - division-free EXACT IoU predicate:
//     RN_f32(inter/un) > 0.45f  <=>  (double)inter > ((double)0.45f + 2^-26)*(double)un

typedef unsigned long long u64;

#define N_IMG 8
#define A     16384
#define NCLS  21
#define NC    20
#define TOPK  100
#define PROB_THR 0.05f

#define TN     512         // nms threads (8 waves)
#define NSLOT  32          // scores per thread (A / TN / 4 float4s = 8 -> 32 floats)
#define NBIN   1152        // score-bit bins: (bits>>15) spans 31385..32512 for (0.05,1]
#define BINOFF 31385
#define CAPC   1024        // chunk capacity (sorted)
#define TARGET 600         // aim chunk size (expected pops ~150-250)

#define MIDTHR ((double)0.45f + 0x1p-26)

__device__ __forceinline__ u64 pk(float v, int i) {
    return (v > 0.f) ? (((u64)__float_as_uint(v) << 32) | (u64)(unsigned)(~(unsigned)i)) : 0ull;
}
__device__ __forceinline__ float upv(u64 k) { return __uint_as_float((unsigned)(k >> 32)); }
__device__ __forceinline__ int   upi(u64 k) { return (int)(~(unsigned)k); }
__device__ __forceinline__ u64 umx(u64 a, u64 b) { return a > b ? a : b; }

__device__ __forceinline__ int binOf(float s) {
    int b = (int)(__float_as_uint(s) >> 15) - BINOFF;
    return b < 0 ? 0 : (b > NBIN - 1 ? NBIN - 1 : b);
}

// exact ref predicate: RN(inter/union) > 0.45f  (union = as_ + ab - inter, add commutes)
__device__ __forceinline__ bool killp(float4 b, float ab, float4 s, float as_) {
    float lx = fmaxf(s.x, b.x), ly = fmaxf(s.y, b.y);
    float rx = fminf(s.z, b.z), ry = fminf(s.w, b.w);
    float iw = fmaxf(rx - lx, 0.f), ih = fmaxf(ry - ly, 0.f);
    float inter = iw * ih;
    float un = as_ + ab - inter;
    return (double)inter > MIDTHR * (double)un;
}

// Kernel 1: softmax + threshold -> scores[N][NC][A]; SSD decode -> clamped corner boxes.
// Identical arithmetic order to R1-R4 (absmax 0.0); cls loads now LDS-staged (coalesced).
__global__ __launch_bounds__(256) void preprocess_kernel(
    const float* __restrict__ cls, const float* __restrict__ reg,
    const float* __restrict__ anc, float4* __restrict__ boxes,
    float* __restrict__ scores) {
    __shared__ __align__(16) float lcls[256 * NCLS];   // 21504 B
    const int tid = threadIdx.x;
    const int t = blockIdx.x * 256 + tid;

    // coalesced stage: 1344 float4s (block base 21504 B, 16B-aligned)
    const float4* src = (const float4*)(cls + (size_t)blockIdx.x * (256 * NCLS));
    float4* dst = (float4*)lcls;
    for (int i = tid; i < (256 * NCLS) / 4; i += 256) dst[i] = src[i];
    __syncthreads();

    const int n = t >> 14;
    const int a = t & (A - 1);
    const float* c = lcls + tid * NCLS;
    float z[NCLS];
    float m = -1e30f;
#pragma unroll
    for (int k = 0; k < NCLS; ++k) { z[k] = c[k]; m = fmaxf(m, z[k]); }
    float s = 0.f;
#pragma unroll
    for (int k = 0; k < NCLS; ++k) { z[k] = expf(z[k] - m); s += z[k]; }
    const float inv = 1.f / s;
#pragma unroll
    for (int k = 0; k < NC; ++k) {
        float p = z[k + 1] * inv;
        scores[(((size_t)n * NC + k) << 14) + a] = (p > PROB_THR) ? p : -1.f;
    }

    const float4 l4 = ((const float4*)reg)[t];
    const float4 an = ((const float4*)anc)[a];
    const float cx = an.x + l4.x * 0.1f * an.z;
    const float cy = an.y + l4.y * 0.1f * an.w;
    const float w  = an.z * expf(l4.z * 0.2f);
    const float h  = an.w * expf(l4.w * 0.2f);
    float x0 = fminf(fmaxf(cx - 0.5f * w, 0.f), 1.f);
    float y0 = fminf(fmaxf(cy - 0.5f * h, 0.f), 1.f);
    float x1 = fminf(fmaxf(cx + 0.5f * w, 0.f), 1.f);
    float y1 = fminf(fmaxf(cy + 0.5f * h, 0.f), 1.f);
    boxes[t] = make_float4(x0, y0, x1, y1);
}

// Kernel 2: one workgroup per (n, ci). Histogram-select -> sort -> lazy walk.
__global__ __launch_bounds__(TN) void nms_kernel(
    const float4* __restrict__ boxes, const float* __restrict__ scores,
    float* __restrict__ rows) {
    __shared__ int bins[NBIN];
    __shared__ u64 skey[CAPC];
    __shared__ __align__(16) float4 sbox[CAPC];
    __shared__ u64 red8[TN / 64];
    __shared__ u64 bkey;
    __shared__ __align__(16) float4 bbox;
    __shared__ int sint[3];   // 0:B  1:cnt  2:degenerate

    const int blk = blockIdx.x, n = blk / NC, ci = blk % NC;
    const int tid = threadIdx.x, lane = tid & 63, w = tid >> 6;
    const float* gs = scores + ((size_t)blk << 14);
    const float4* gb = boxes + ((size_t)n << 14);
    float* grows = rows + (size_t)blk * 600;

    // scores -> registers (coalesced float4; anchor of slot t = (tid<<2)+(t>>2)*2048+(t&3))
    float sc[NSLOT];
    const float4* gs4 = (const float4*)gs;
#pragma unroll
    for (int k = 0; k < NSLOT / 4; ++k) {
        float4 v = gs4[tid + (k << 9)];
        sc[k * 4 + 0] = v.x; sc[k * 4 + 1] = v.y; sc[k * 4 + 2] = v.z; sc[k * 4 + 3] = v.w;
    }
#define AIDX(t_) ((tid << 2) + (((t_) >> 2) << 11) + ((t_) & 3))

    float4 accA, accB;
    float arA = 0.f, arB = 0.f;
    int na = 0;
    u64 filter = ~0ull;
    bool done = false;

    while (!done && na < TOPK) {
        // ---- filtered histogram ----
        for (int i = tid; i < NBIN; i += TN) bins[i] = 0;
        if (tid == 0) { sint[1] = 0; sint[2] = 0; }
        __syncthreads();
#pragma unroll
        for (int t = 0; t < NSLOT; ++t) {
            float s = sc[t];
            if (s > 0.f) {
                u64 kk = pk(s, AIDX(t));
                if (kk < filter) atomicAdd(&bins[binOf(s)], 1);
            }
        }
        __syncthreads();

        // ---- select bin threshold B (wave0): smallest window >= min(TARGET,total), <= CAPC ----
        if (tid < 64) {
            int lsum[18];
            int tot = 0;
#pragma unroll
            for (int k = 0; k < 18; ++k) { lsum[k] = bins[tid * 18 + k]; tot += lsum[k]; }
            int pfx = tot;
#pragma unroll
            for (int off = 1; off < 64; off <<= 1) {
                int o = __shfl_up(pfx, off, 64);
                if (lane >= off) pfx += o;
            }
            const int totalAll = __shfl(pfx, 63, 64);
            const int sufAbove = totalAll - pfx;
            const int tgt = totalAll < TARGET ? totalAll : TARGET;
            int run = 0, b1 = -1, b2 = 1 << 30;
#pragma unroll
            for (int k = 17; k >= 0; --k) {
                run += lsum[k];
                int suf = sufAbove + run;
                int b = tid * 18 + k;
                if (suf >= tgt && b > b1) b1 = b;
                if (suf <= CAPC && b < b2) b2 = b;
            }
#pragma unroll
            for (int off = 1; off < 64; off <<= 1) {
                int o1 = __shfl_xor(b1, off, 64); if (o1 > b1) b1 = o1;
                int o2 = __shfl_xor(b2, off, 64); if (o2 < b2) b2 = o2;
            }
            if (lane == 0) {
                sint[0] = b1 > b2 ? b1 : b2;
                sint[2] = (b2 == (1 << 30)) ? 1 : 0;
            }
        }
        __syncthreads();
        const int B = sint[0];
        const int degen = sint[2];

        if (!degen) {
            // ---- compact keys of bins >= B (order arbitrary; sort fixes it) ----
#pragma unroll
            for (int t = 0; t < NSLOT; ++t) {
                float s = sc[t];
                if (s > 0.f && binOf(s) >= B) {
                    u64 kk = pk(s, AIDX(t));
                    if (kk < filter) { int sl = atomicAdd(&sint[1], 1); skey[sl] = kk; }
                }
            }
            __syncthreads();
            const int T = sint[1];
            if (T == 0) break;                       // exhausted
            for (int i = T + tid; i < CAPC; i += TN) skey[i] = 0ull;

            // ---- bitonic sort 1024 u64 descending ----
            for (int kk2 = 2; kk2 <= CAPC; kk2 <<= 1) {
                for (int j = kk2 >> 1; j > 0; j >>= 1) {
                    __syncthreads();
                    int i = ((tid & ~(j - 1)) << 1) | (tid & (j - 1));
                    u64 a = skey[i], b = skey[i + j];
                    bool mx = ((i & kk2) == 0);      // descending overall
                    if (mx ? (a < b) : (a > b)) { skey[i] = b; skey[i + j] = a; }
                }
            }
            __syncthreads();

            // ---- prefetch candidate boxes in sorted order ----
            for (int p = tid; p < CAPC; p += TN) {
                u64 kk = skey[p];
                if (kk) sbox[p] = gb[upi(kk)];
            }
            __syncthreads();

            // ---- lazy walk (all waves redundantly; accepted distributed over 64 lanes) ----
            for (int p = 0; p < T; ++p) {
                u64 kk = skey[p];
                filter = kk;
                float4 cb = sbox[p];
                float ca = (cb.z - cb.x) * (cb.w - cb.y);
                bool kill = false;
                if (lane < na)      kill = killp(cb, ca, accA, arA);
                if (lane + 64 < na) kill = kill || killp(cb, ca, accB, arB);
                if (!__any(kill)) {
                    if (tid == 0) {
                        float* o = grows + na * 6;
                        o[0] = cb.x; o[1] = cb.y; o[2] = cb.z; o[3] = cb.w;
                        o[4] = upv(kk); o[5] = (float)(ci + 1);
                    }
                    if (na < 64) { if (lane == na) { accA = cb; arA = ca; } }
                    else if (lane == na - 64) { accB = cb; arB = ca; }
                    ++na;
                    if (na == TOPK) { done = true; break; }
                }
            }
            // next refill iteration's skey writes are gated by the two barriers
            // (zero/count -> select) before any compact store, so no race with
            // waves still finishing this walk.
        } else {
            // ---- degenerate (one bin > CAPC; never on real data): single extractions ----
            while (na < TOPK) {
                u64 best = 0ull;
#pragma unroll
                for (int t = 0; t < NSLOT; ++t) {
                    float s = sc[t];
                    if (s > 0.f) {
                        u64 kk = pk(s, AIDX(t));
                        if (kk < filter && kk > best) best = kk;
                    }
                }
#pragma unroll
                for (int off = 1; off < 64; off <<= 1) best = umx(best, __shfl_xor(best, off, 64));
                if (lane == 0) red8[w] = best;
                __syncthreads();
                if (tid == 0) {
                    u64 bb = red8[0];
#pragma unroll
                    for (int q = 1; q < TN / 64; ++q) bb = umx(bb, red8[q]);
                    bkey = bb;
                    if (bb) bbox = gb[upi(bb)];
                }
                __syncthreads();
                u64 kk = bkey;
                if (!kk) break;                       // exhausted
                filter = kk;
                float4 cb = bbox;
                float ca = (cb.z - cb.x) * (cb.w - cb.y);
                bool kill = false;
                if (lane < na)      kill = killp(cb, ca, accA, arA);
                if (lane + 64 < na) kill = kill || killp(cb, ca, accB, arB);
                if (!__any(kill)) {
                    if (tid == 0) {
                        float* o = grows + na * 6;
                        o[0] = cb.x; o[1] = cb.y; o[2] = cb.z; o[3] = cb.w;
                        o[4] = upv(kk); o[5] = (float)(ci + 1);
                    }
                    if (na < 64) { if (lane == na) { accA = cb; arA = ca; } }
                    else if (lane == na - 64) { accB = cb; arB = ca; }
                    ++na;
                }
                __syncthreads();
            }
            break;
        }
    }
    // remaining rows are zeros (matches ref valid=False rows)
    for (int j = na * 6 + tid; j < 600; j += TN) grows[j] = 0.f;
#undef AIDX
}

// Kernel 3: per image, 20-way merge of per-class sorted row lists (1 wave / image).
// Rows are sorted desc by (score, anchor-idx) per class; flat ref tie-break is
// (score desc, ci*100+pos asc) -> one u64 key. Exact lax.top_k order.
__global__ __launch_bounds__(64) void topk_kernel(
    const float* __restrict__ rows, float* __restrict__ out) {
    const int n = blockIdx.x, lane = threadIdx.x;
    const float* base = rows + (size_t)n * (NC * 600);
    float* o = out + (size_t)n * 600;

    float cur[6] = {0, 0, 0, 0, 0, 0}, nxt[6] = {0, 0, 0, 0, 0, 0};
    u64 ckey = 0, nkey = 0;
    int nextp = 2;
    if (lane < NC) {
        const float* r = base + lane * 600;
#pragma unroll
        for (int i = 0; i < 6; ++i) cur[i] = r[i];
        if (cur[4] > 0.f)
            ckey = ((u64)__float_as_uint(cur[4]) << 32) | (u64)(0xFFFFFFFFu - (unsigned)(lane * TOPK));
#pragma unroll
        for (int i = 0; i < 6; ++i) nxt[i] = r[6 + i];
        if (nxt[4] > 0.f)
            nkey = ((u64)__float_as_uint(nxt[4]) << 32) | (u64)(0xFFFFFFFFu - (unsigned)(lane * TOPK + 1));
    }
    for (int k = 0; k < TOPK; ++k) {
        u64 m = ckey;
#pragma unroll
        for (int off = 32; off > 0; off >>= 1) { u64 v = __shfl_xor(m, off, 64); m = m > v ? m : v; }
        if (m == 0ull) {
            for (int j = k * 6 + lane; j < 600; j += 64) o[j] = 0.f;
            return;
        }
        if (ckey == m) {
            float* d = o + k * 6;
#pragma unroll
            for (int i = 0; i < 6; ++i) d[i] = cur[i];
#pragma unroll
            for (int i = 0; i < 6; ++i) cur[i] = nxt[i];
            ckey = nkey;
            nkey = 0;
            if (nextp < TOPK) {
                const float* r = base + lane * 600 + nextp * 6;
#pragma unroll
                for (int i = 0; i < 6; ++i) nxt[i] = r[i];
                if (nxt[4] > 0.f)
                    nkey = ((u64)__float_as_uint(nxt[4]) << 32) |
                           (u64)(0xFFFFFFFFu - (unsigned)(lane * TOPK + nextp));
            }
            ++nextp;
        }
    }
}

extern "C" void kernel_launch(void* const* d_in, const int* in_sizes, int n_in,
                              void* d_out, int out_size, void* d_ws, size_t ws_size,
                              hipStream_t stream) {
    const float* cls = (const float*)d_in[0];   // [8,16384,21]
    const float* reg = (const float*)d_in[1];   // [8,16384,4]
    const float* anc = (const float*)d_in[2];   // [16384,4]
    float* out = (float*)d_out;                 // [8,100,6]

    // ws layout (floats): boxes 524288 | scores 2621440 | rows 96000
    float* boxes  = (float*)d_ws;
    float* scores = boxes + (size_t)N_IMG * A * 4;
    float* rows   = scores + (size_t)N_IMG * NC * A;

    preprocess_kernel<<<(N_IMG * A) / 256, 256, 0, stream>>>(cls, reg, anc, (float4*)boxes, scores);
    nms_kernel<<<N_IMG * NC, TN, 0, stream>>>((const float4*)boxes, scores, rows);
    topk_kernel<<<N_IMG, 64, 0, stream>>>(rows, out);
}

// Round 6
// 144.209 us; speedup vs baseline: 8.7187x; 1.2189x over previous
//
#include <hip/hip_runtime.h>

// Detection post-process: softmax -> decode -> per-class LAZY NMS -> top-100.
// N=8 images, A=16384 anchors, C=21 classes (class 0 = background).
//
// R5 lessons (counters): bitonic-1024 (55 stages, 8-way u64 bank conflicts, 446k
// conflict cyc) + unprefetched serial walk (dependent ~120cyc LDS chains) + topk's
// single-wave serial merge (~45us) dominate. R6: 512-chunk sort + LDS swizzle +
// ballot-aggregated compaction + prefetched walk; topk = one bitonic sort of all
// 2048 candidate keys per image.
// Exactness invariants (absmax 0.0 since R1):
//   - u64 key = (score_bits<<32)|~idx  => exact (score desc, idx asc) total order
//   - monotone bin(float bits) => bin-threshold selection is a key-order cut
//   - lazy NMS: dead entries never kill => test pops against accepted set only
//   - division-free EXACT IoU predicate:
//     RN_f32(inter/un) > 0.45f  <=>  (double)inter > ((double)0.45f + 2^-26)*(double)un

typedef unsigned long long u64;

#define N_IMG 8
#define A     16384
#define NCLS  21
#define NC    20
#define TOPK  100
#define PROB_THR 0.05f

#define TN     512         // nms threads (8 waves)
#define NSLOT  32          // scores per thread
#define NBIN   1152        // score-bit bins: (bits>>15)-31385 spans (0.05,1]
#define BINOFF 31385
#define CAPC   512         // chunk capacity (sorted); expected pops ~150-250
#define TARGET 384

#define PHYS(i) ((i) + ((i) >> 4))   // LDS u64 swizzle: breaks power-of-2 strides

#define MIDTHR ((double)0.45f + 0x1p-26)

__device__ __forceinline__ u64 pk(float v, int i) {
    return (v > 0.f) ? (((u64)__float_as_uint(v) << 32) | (u64)(unsigned)(~(unsigned)i)) : 0ull;
}
__device__ __forceinline__ float upv(u64 k) { return __uint_as_float((unsigned)(k >> 32)); }
__device__ __forceinline__ int   upi(u64 k) { return (int)(~(unsigned)k); }
__device__ __forceinline__ u64 umx(u64 a, u64 b) { return a > b ? a : b; }

__device__ __forceinline__ int binOf(float s) {
    int b = (int)(__float_as_uint(s) >> 15) - BINOFF;
    return b < 0 ? 0 : (b > NBIN - 1 ? NBIN - 1 : b);
}

// exact ref predicate: RN(inter/union) > 0.45f
__device__ __forceinline__ bool killp(float4 b, float ab, float4 s, float as_) {
    float lx = fmaxf(s.x, b.x), ly = fmaxf(s.y, b.y);
    float rx = fminf(s.z, b.z), ry = fminf(s.w, b.w);
    float iw = fmaxf(rx - lx, 0.f), ih = fmaxf(ry - ly, 0.f);
    float inter = iw * ih;
    float un = as_ + ab - inter;
    return (double)inter > MIDTHR * (double)un;
}

// Kernel 1: softmax + threshold -> scores[N][NC][A]; SSD decode -> clamped corner boxes.
__global__ __launch_bounds__(256) void preprocess_kernel(
    const float* __restrict__ cls, const float* __restrict__ reg,
    const float* __restrict__ anc, float4* __restrict__ boxes,
    float* __restrict__ scores) {
    __shared__ __align__(16) float lcls[256 * NCLS];
    const int tid = threadIdx.x;
    const int t = blockIdx.x * 256 + tid;

    const float4* src = (const float4*)(cls + (size_t)blockIdx.x * (256 * NCLS));
    float4* dst = (float4*)lcls;
    for (int i = tid; i < (256 * NCLS) / 4; i += 256) dst[i] = src[i];
    __syncthreads();

    const int n = t >> 14;
    const int a = t & (A - 1);
    const float* c = lcls + tid * NCLS;
    float z[NCLS];
    float m = -1e30f;
#pragma unroll
    for (int k = 0; k < NCLS; ++k) { z[k] = c[k]; m = fmaxf(m, z[k]); }
    float s = 0.f;
#pragma unroll
    for (int k = 0; k < NCLS; ++k) { z[k] = expf(z[k] - m); s += z[k]; }
    const float inv = 1.f / s;
#pragma unroll
    for (int k = 0; k < NC; ++k) {
        float p = z[k + 1] * inv;
        scores[(((size_t)n * NC + k) << 14) + a] = (p > PROB_THR) ? p : -1.f;
    }

    const float4 l4 = ((const float4*)reg)[t];
    const float4 an = ((const float4*)anc)[a];
    const float cx = an.x + l4.x * 0.1f * an.z;
    const float cy = an.y + l4.y * 0.1f * an.w;
    const float w  = an.z * expf(l4.z * 0.2f);
    const float h  = an.w * expf(l4.w * 0.2f);
    float x0 = fminf(fmaxf(cx - 0.5f * w, 0.f), 1.f);
    float y0 = fminf(fmaxf(cy - 0.5f * h, 0.f), 1.f);
    float x1 = fminf(fmaxf(cx + 0.5f * w, 0.f), 1.f);
    float y1 = fminf(fmaxf(cy + 0.5f * h, 0.f), 1.f);
    boxes[t] = make_float4(x0, y0, x1, y1);
}

// Kernel 2: one workgroup per (n, ci). Histogram-select -> sort-512 -> lazy walk.
__global__ __launch_bounds__(TN) void nms_kernel(
    const float4* __restrict__ boxes, const float* __restrict__ scores,
    float* __restrict__ rows) {
    __shared__ int bins[NBIN];
    __shared__ u64 skey[PHYS(CAPC - 1) + 2];
    __shared__ __align__(16) float4 sbox[CAPC];
    __shared__ u64 red8[TN / 64];
    __shared__ u64 bkey;
    __shared__ __align__(16) float4 bbox;
    __shared__ int sint[3];   // 0:B  1:cnt  2:degenerate

    const int blk = blockIdx.x, n = blk / NC, ci = blk % NC;
    const int tid = threadIdx.x, lane = tid & 63, w = tid >> 6;
    const float* gs = scores + ((size_t)blk << 14);
    const float4* gb = boxes + ((size_t)n << 14);
    float* grows = rows + (size_t)blk * 600;

    // scores -> registers (coalesced float4)
    float sc[NSLOT];
    const float4* gs4 = (const float4*)gs;
#pragma unroll
    for (int k = 0; k < NSLOT / 4; ++k) {
        float4 v = gs4[tid + (k << 9)];
        sc[k * 4 + 0] = v.x; sc[k * 4 + 1] = v.y; sc[k * 4 + 2] = v.z; sc[k * 4 + 3] = v.w;
    }
#define AIDX(t_) ((tid << 2) + (((t_) >> 2) << 11) + ((t_) & 3))

    float4 accA, accB;
    float arA = 0.f, arB = 0.f;
    int na = 0;
    u64 filter = ~0ull;
    bool done = false;

    while (!done && na < TOPK) {
        // ---- filtered histogram ----
        for (int i = tid; i < NBIN; i += TN) bins[i] = 0;
        if (tid == 0) { sint[1] = 0; sint[2] = 0; }
        __syncthreads();
#pragma unroll
        for (int t = 0; t < NSLOT; ++t) {
            float s = sc[t];
            if (s > 0.f) {
                u64 kk = pk(s, AIDX(t));
                if (kk < filter) atomicAdd(&bins[binOf(s)], 1);
            }
        }
        __syncthreads();

        // ---- select bin threshold B (wave0) ----
        if (tid < 64) {
            int lsum[18];
            int tot = 0;
#pragma unroll
            for (int k = 0; k < 18; ++k) { lsum[k] = bins[tid * 18 + k]; tot += lsum[k]; }
            int pfx = tot;
#pragma unroll
            for (int off = 1; off < 64; off <<= 1) {
                int o = __shfl_up(pfx, off, 64);
                if (lane >= off) pfx += o;
            }
            const int totalAll = __shfl(pfx, 63, 64);
            const int sufAbove = totalAll - pfx;
            const int tgt = totalAll < TARGET ? totalAll : TARGET;
            int run = 0, b1 = -1, b2 = 1 << 30;
#pragma unroll
            for (int k = 17; k >= 0; --k) {
                run += lsum[k];
                int suf = sufAbove + run;
                int b = tid * 18 + k;
                if (suf >= tgt && b > b1) b1 = b;
                if (suf <= CAPC && b < b2) b2 = b;
            }
#pragma unroll
            for (int off = 1; off < 64; off <<= 1) {
                int o1 = __shfl_xor(b1, off, 64); if (o1 > b1) b1 = o1;
                int o2 = __shfl_xor(b2, off, 64); if (o2 < b2) b2 = o2;
            }
            if (lane == 0) {
                sint[0] = b1 > b2 ? b1 : b2;
                sint[2] = (b2 == (1 << 30)) ? 1 : 0;
            }
        }
        __syncthreads();
        const int B = sint[0];
        const int degen = sint[2];

        if (!degen) {
            // ---- compact keys of bins >= B (ballot-aggregated; order fixed by sort) ----
#pragma unroll
            for (int t = 0; t < NSLOT; ++t) {
                float s = sc[t];
                bool pred = false; u64 kk = 0ull;
                if (s > 0.f && binOf(s) >= B) {
                    kk = pk(s, AIDX(t));
                    pred = (kk < filter);
                }
                u64 m = __ballot(pred);
                if (m) {
                    int bse = 0;
                    if (lane == 0) bse = atomicAdd(&sint[1], __popcll(m));
                    bse = __shfl(bse, 0, 64);
                    if (pred) {
                        int sl = bse + __popcll(m & ((1ull << lane) - 1ull));
                        skey[PHYS(sl)] = kk;
                    }
                }
            }
            __syncthreads();
            const int T = sint[1];
            if (T == 0) break;                       // exhausted
            for (int i = T + tid; i < CAPC; i += TN) skey[PHYS(i)] = 0ull;

            // ---- bitonic sort 512 u64 descending (swizzled LDS) ----
            for (int kk2 = 2; kk2 <= CAPC; kk2 <<= 1) {
                for (int j = kk2 >> 1; j > 0; j >>= 1) {
                    __syncthreads();
                    if (tid < CAPC / 2) {
                        int i = ((tid & ~(j - 1)) << 1) | (tid & (j - 1));
                        int p1 = PHYS(i), p2 = PHYS(i + j);
                        u64 a = skey[p1], b = skey[p2];
                        if (((i & kk2) == 0) ? (a < b) : (a > b)) { skey[p1] = b; skey[p2] = a; }
                    }
                }
            }
            __syncthreads();

            // ---- prefetch candidate boxes in sorted order ----
            for (int p = tid; p < CAPC; p += TN) {
                u64 kk = skey[PHYS(p)];
                if (kk) sbox[p] = gb[upi(kk)];
            }
            __syncthreads();

            // ---- lazy walk (all waves redundantly; +1-deep register prefetch) ----
            u64 nk = skey[PHYS(0)];
            float4 nb = sbox[0];
            for (int p = 0; p < T; ++p) {
                u64 kk = nk; float4 cb = nb;
                if (p + 1 < T) { nk = skey[PHYS(p + 1)]; nb = sbox[p + 1]; }
                filter = kk;
                float ca = (cb.z - cb.x) * (cb.w - cb.y);
                bool kill = false;
                if (lane < na)      kill = killp(cb, ca, accA, arA);
                if (lane + 64 < na) kill = kill || killp(cb, ca, accB, arB);
                if (!__any(kill)) {
                    if (tid == 0) {
                        float* o = grows + na * 6;
                        o[0] = cb.x; o[1] = cb.y; o[2] = cb.z; o[3] = cb.w;
                        o[4] = upv(kk); o[5] = (float)(ci + 1);
                    }
                    if (na < 64) { if (lane == na) { accA = cb; arA = ca; } }
                    else if (lane == na - 64) { accB = cb; arB = ca; }
                    ++na;
                    if (na == TOPK) { done = true; break; }
                }
            }
            // next refill's LDS writes are gated by two barriers before any store,
            // so no race with waves still finishing this walk.
        } else {
            // ---- degenerate (one bin > CAPC; never on real data): single extractions ----
            while (na < TOPK) {
                u64 best = 0ull;
#pragma unroll
                for (int t = 0; t < NSLOT; ++t) {
                    float s = sc[t];
                    if (s > 0.f) {
                        u64 kk = pk(s, AIDX(t));
                        if (kk < filter && kk > best) best = kk;
                    }
                }
#pragma unroll
                for (int off = 1; off < 64; off <<= 1) best = umx(best, __shfl_xor(best, off, 64));
                if (lane == 0) red8[w] = best;
                __syncthreads();
                if (tid == 0) {
                    u64 bb = red8[0];
#pragma unroll
                    for (int q = 1; q < TN / 64; ++q) bb = umx(bb, red8[q]);
                    bkey = bb;
                    if (bb) bbox = gb[upi(bb)];
                }
                __syncthreads();
                u64 kk = bkey;
                if (!kk) break;
                filter = kk;
                float4 cb = bbox;
                float ca = (cb.z - cb.x) * (cb.w - cb.y);
                bool kill = false;
                if (lane < na)      kill = killp(cb, ca, accA, arA);
                if (lane + 64 < na) kill = kill || killp(cb, ca, accB, arB);
                if (!__any(kill)) {
                    if (tid == 0) {
                        float* o = grows + na * 6;
                        o[0] = cb.x; o[1] = cb.y; o[2] = cb.z; o[3] = cb.w;
                        o[4] = upv(kk); o[5] = (float)(ci + 1);
                    }
                    if (na < 64) { if (lane == na) { accA = cb; arA = ca; } }
                    else if (lane == na - 64) { accB = cb; arB = ca; }
                    ++na;
                }
                __syncthreads();
            }
            break;
        }
    }
    for (int j = na * 6 + tid; j < 600; j += TN) grows[j] = 0.f;
#undef AIDX
}

// Kernel 3: per image, bitonic sort of all 2048 padded candidate keys, gather top-100.
// key = (score_bits<<32) | (0xFFFFFFFF - flat_j), flat_j = (ci+1)*100 + pos. Exact
// lax.top_k order for positive scores; zero-score selections are all-zero rows in
// both ref (class-0 block / invalid rows) and ours -> value-identical output.
__global__ __launch_bounds__(1024) void topk_kernel(
    const float* __restrict__ rows, float* __restrict__ out) {
    __shared__ u64 skey[PHYS(2047) + 2];
    const int n = blockIdx.x, tid = threadIdx.x;
    const float* base = rows + (size_t)n * (NC * 600);

    for (int e = tid; e < 2048; e += 1024) {
        u64 k = 0ull;
        if (e < 2000) {
            int ci = e / 100, pos = e - ci * 100;
            float s = base[ci * 600 + pos * 6 + 4];
            k = ((u64)__float_as_uint(s) << 32) | (u64)(0xFFFFFFFFu - (unsigned)(e + 100));
        }
        skey[PHYS(e)] = k;
    }
    for (int kk2 = 2; kk2 <= 2048; kk2 <<= 1) {
        for (int j = kk2 >> 1; j > 0; j >>= 1) {
            __syncthreads();
            int i = ((tid & ~(j - 1)) << 1) | (tid & (j - 1));
            int p1 = PHYS(i), p2 = PHYS(i + j);
            u64 a = skey[p1], b = skey[p2];
            if (((i & kk2) == 0) ? (a < b) : (a > b)) { skey[p1] = b; skey[p2] = a; }
        }
    }
    __syncthreads();
    if (tid < 600) {
        int k = tid / 6, f = tid - (tid / 6) * 6;
        u64 kk = skey[PHYS(k)];
        float v = 0.f;
        if ((unsigned)(kk >> 32) != 0u) {
            int e = (int)(0xFFFFFFFFu - (unsigned)kk) - 100;
            int ci = e / 100, pos = e - ci * 100;
            v = base[ci * 600 + pos * 6 + f];
        }
        out[(size_t)n * 600 + tid] = v;
    }
}

extern "C" void kernel_launch(void* const* d_in, const int* in_sizes, int n_in,
                              void* d_out, int out_size, void* d_ws, size_t ws_size,
                              hipStream_t stream) {
    const float* cls = (const float*)d_in[0];   // [8,16384,21]
    const float* reg = (const float*)d_in[1];   // [8,16384,4]
    const float* anc = (const float*)d_in[2];   // [16384,4]
    float* out = (float*)d_out;                 // [8,100,6]

    // ws layout (floats): boxes 524288 | scores 2621440 | rows 96000
    float* boxes  = (float*)d_ws;
    float* scores = boxes + (size_t)N_IMG * A * 4;
    float* rows   = scores + (size_t)N_IMG * NC * A;

    preprocess_kernel<<<(N_IMG * A) / 256, 256, 0, stream>>>(cls, reg, anc, (float4*)boxes, scores);
    nms_kernel<<<N_IMG * NC, TN, 0, stream>>>((const float4*)boxes, scores, rows);
    topk_kernel<<<N_IMG, 1024, 0, stream>>>(rows, out);
}